// Round 10
// baseline (27.585 us; speedup 1.0000x reference)
//
#include <hip/hip_runtime.h>

#define BLK 256
#define NJ 24
#define G 8
#define NG (NJ / G)

__global__ __launch_bounds__(BLK, 2)
void fk_kernel(const float* __restrict__ angles,   // (B, 24)
               const float* __restrict__ Torg,     // (24, 4, 4) row-major
               const float* __restrict__ axes,     // (24, 3)
               float* __restrict__ out,            // (B, 75)
               int B)
{
    __shared__ float sQK[NJ * 8];   // per joint: {qw,qx,qy,qz, otx,oty,otz, pad}
    __shared__ float sAx[NJ * 4];   // axis xyz + pad

    const int tid = threadIdx.x;

    // --- One-time: convert T_org rotations to quaternions (threads 0..23) ---
    if (tid < NJ) {
        const float* o = Torg + tid * 16;
        const float m00=o[0], m01=o[1], m02=o[2];
        const float m10=o[4], m11=o[5], m12=o[6];
        const float m20=o[8], m21=o[9], m22=o[10];
        const float tr = m00 + m11 + m22;
        float qw, qx, qy, qz;
        if (tr > 0.f) {
            const float S = sqrtf(tr + 1.f) * 2.f;
            qw = 0.25f * S;
            qx = (m21 - m12) / S;
            qy = (m02 - m20) / S;
            qz = (m10 - m01) / S;
        } else if (m00 > m11 && m00 > m22) {
            const float S = sqrtf(1.f + m00 - m11 - m22) * 2.f;
            qw = (m21 - m12) / S;
            qx = 0.25f * S;
            qy = (m01 + m10) / S;
            qz = (m02 + m20) / S;
        } else if (m11 > m22) {
            const float S = sqrtf(1.f + m11 - m00 - m22) * 2.f;
            qw = (m02 - m20) / S;
            qx = (m01 + m10) / S;
            qy = 0.25f * S;
            qz = (m12 + m21) / S;
        } else {
            const float S = sqrtf(1.f + m22 - m00 - m11) * 2.f;
            qw = (m10 - m01) / S;
            qx = (m02 + m20) / S;
            qy = (m12 + m21) / S;
            qz = 0.25f * S;
        }
        float* q = &sQK[tid * 8];
        q[0] = qw; q[1] = qx; q[2] = qy; q[3] = qz;
        q[4] = o[3]; q[5] = o[7]; q[6] = o[11]; q[7] = 0.f;   // O_t
        float* ax = &sAx[tid * 4];
        ax[0] = axes[tid*3+0]; ax[1] = axes[tid*3+1]; ax[2] = axes[tid*3+2]; ax[3] = 0.f;
    }
    __syncthreads();

    const int b = blockIdx.x * BLK + tid;
    const float4* ap = reinterpret_cast<const float4*>(angles + (size_t)b * NJ);
    float* orow = out + (size_t)b * 75;

    // Running transform as quaternion Q + translation t.
    float Qw = 1.f, Qx = 0.f, Qy = 0.f, Qz = 0.f;
    float tx = 0.f, ty = 0.f, tz = 0.f;

    // base_pos: one dwordx3 store (4-B aligned float3)
    *reinterpret_cast<float3*>(orow) = make_float3(0.f, 0.f, 0.f);

    // Software-pipelined angle loads (named float4 regs only).
    float4 av0 = ap[0], av1 = ap[1];

    #pragma unroll 1
    for (int g = 0; g < NG; ++g) {
        float4 nv0, nv1;
        if (g + 1 < NG) { nv0 = ap[2*g + 2]; nv1 = ap[2*g + 3]; }

        float a[G];
        a[0]=av0.x; a[1]=av0.y; a[2]=av0.z; a[3]=av0.w;
        a[4]=av1.x; a[5]=av1.y; a[6]=av1.z; a[7]=av1.w;

        // --- Phase A: u_j = qO_j * q_j for 8 joints (independent, ILP) ---
        float U[G][4];
        float OT[G][3];
        #pragma unroll
        for (int u = 0; u < G; ++u) {
            const int j = g * G + u;
            const float4 qo = *reinterpret_cast<const float4*>(&sQK[j*8]);
            const float4 ot = *reinterpret_cast<const float4*>(&sQK[j*8+4]);
            const float4 ax = *reinterpret_cast<const float4*>(&sAx[j*4]);
            OT[u][0] = ot.x; OT[u][1] = ot.y; OT[u][2] = ot.z;

            const float h = 0.5f * a[u];
            const float s = __sinf(h);
            const float c = __cosf(h);
            const float bx = s * ax.x, by = s * ax.y, bz = s * ax.z;

            U[u][0] = qo.x*c  - qo.y*bx - qo.z*by - qo.w*bz;
            U[u][1] = qo.x*bx + qo.y*c  + qo.z*bz - qo.w*by;
            U[u][2] = qo.x*by - qo.y*bz + qo.z*c  + qo.w*bx;
            U[u][3] = qo.x*bz + qo.y*by - qo.z*bx + qo.w*c;
        }

        // --- Phase B: serial chain; store each position the moment it
        // exists (fire-and-forget dwordx3 -> HBM writes overlap compute) ---
        #pragma unroll
        for (int u = 0; u < G; ++u) {
            const int j = g * G + u;
            const float ox = OT[u][0], oy = OT[u][1], oz = OT[u][2];

            // t_child = t + R(Q)*O_t   (v' = v + 2*qv x (qv x v + w v))
            const float cx = Qy*oz - Qz*oy + Qw*ox;
            const float cy = Qz*ox - Qx*oz + Qw*oy;
            const float cz = Qx*oy - Qy*ox + Qw*oz;
            const float dx = Qy*cz - Qz*cy;
            const float dy = Qz*cx - Qx*cz;
            const float dz = Qx*cy - Qy*cx;
            tx = tx + ox + 2.f*dx;
            ty = ty + oy + 2.f*dy;
            tz = tz + oz + 2.f*dz;

            // Q = Q * U[u]   (Hamilton)
            const float uw = U[u][0], ux = U[u][1], uy = U[u][2], uz = U[u][3];
            const float nw = Qw*uw - Qx*ux - Qy*uy - Qz*uz;
            const float nx = Qw*ux + Qx*uw + Qy*uz - Qz*uy;
            const float ny = Qw*uy - Qx*uz + Qy*uw + Qz*ux;
            const float nz = Qw*uz + Qx*uy - Qy*ux + Qz*uw;
            Qw = nw; Qx = nx; Qy = ny; Qz = nz;

            *reinterpret_cast<float3*>(orow + 3 + 3*j) = make_float3(tx, ty, tz);
        }

        av0 = nv0; av1 = nv1;
    }
}

extern "C" void kernel_launch(void* const* d_in, const int* in_sizes, int n_in,
                              void* d_out, int out_size, void* d_ws, size_t ws_size,
                              hipStream_t stream) {
    const float* angles = (const float*)d_in[0];
    const float* Torg   = (const float*)d_in[1];
    const float* axes   = (const float*)d_in[2];
    float* out = (float*)d_out;

    const int B = in_sizes[0] / NJ;          // 131072
    const int grid = (B + BLK - 1) / BLK;    // 512

    fk_kernel<<<grid, BLK, 0, stream>>>(angles, Torg, axes, out, B);
}

// Round 12
// 19.133 us; speedup vs baseline: 1.4417x; 1.4417x over previous
//
#include <hip/hip_runtime.h>

#define BLK 256
#define NJ 24
#define G 8
#define NG (NJ / G)

typedef float vf4 __attribute__((ext_vector_type(4)));  // native vec for nontemporal builtin

__global__ __launch_bounds__(BLK, 2)
void fk_kernel(const float* __restrict__ angles,   // (B, 24)
               const float* __restrict__ Torg,     // (24, 4, 4) row-major
               const float* __restrict__ axes,     // (24, 3)
               float* __restrict__ out,            // (B, 75)
               int B)
{
    __shared__ float stage[BLK * 75];
    __shared__ float sQK[NJ * 8];   // per joint: {qw,qx,qy,qz, otx,oty,otz, pad}
    __shared__ float sAx[NJ * 4];   // axis xyz + pad

    const int tid = threadIdx.x;
    const int b = blockIdx.x * BLK + tid;

    // Prefetch ALL 24 angles up front: 6 float4 loads in flight, latency
    // hidden under the prologue + first compute group.
    const float4* ap = reinterpret_cast<const float4*>(angles + (size_t)b * NJ);
    const float4 av0 = ap[0], av1 = ap[1], av2 = ap[2];
    const float4 av3 = ap[3], av4 = ap[4], av5 = ap[5];

    // --- One-time: convert T_org rotations to quaternions (threads 0..23) ---
    if (tid < NJ) {
        const float* o = Torg + tid * 16;
        const float m00=o[0], m01=o[1], m02=o[2];
        const float m10=o[4], m11=o[5], m12=o[6];
        const float m20=o[8], m21=o[9], m22=o[10];
        const float tr = m00 + m11 + m22;
        float qw, qx, qy, qz;
        if (tr > 0.f) {
            const float S = sqrtf(tr + 1.f) * 2.f;
            qw = 0.25f * S;
            qx = (m21 - m12) / S;
            qy = (m02 - m20) / S;
            qz = (m10 - m01) / S;
        } else if (m00 > m11 && m00 > m22) {
            const float S = sqrtf(1.f + m00 - m11 - m22) * 2.f;
            qw = (m21 - m12) / S;
            qx = 0.25f * S;
            qy = (m01 + m10) / S;
            qz = (m02 + m20) / S;
        } else if (m11 > m22) {
            const float S = sqrtf(1.f + m11 - m00 - m22) * 2.f;
            qw = (m02 - m20) / S;
            qx = (m01 + m10) / S;
            qy = 0.25f * S;
            qz = (m12 + m21) / S;
        } else {
            const float S = sqrtf(1.f + m22 - m00 - m11) * 2.f;
            qw = (m10 - m01) / S;
            qx = (m02 + m20) / S;
            qy = (m12 + m21) / S;
            qz = 0.25f * S;
        }
        float* q = &sQK[tid * 8];
        q[0] = qw; q[1] = qx; q[2] = qy; q[3] = qz;
        q[4] = o[3]; q[5] = o[7]; q[6] = o[11]; q[7] = 0.f;   // O_t
        float* ax = &sAx[tid * 4];
        ax[0] = axes[tid*3+0]; ax[1] = axes[tid*3+1]; ax[2] = axes[tid*3+2]; ax[3] = 0.f;
    }
    __syncthreads();

    // Running transform as quaternion Q + translation t.
    float Qw = 1.f, Qx = 0.f, Qy = 0.f, Qz = 0.f;
    float tx = 0.f, ty = 0.f, tz = 0.f;

    float* srow = &stage[tid * 75];
    srow[0] = 0.f; srow[1] = 0.f; srow[2] = 0.f;   // base_pos

    #pragma unroll 1
    for (int g = 0; g < NG; ++g) {
        float a[G];
        if (g == 0) {
            a[0]=av0.x; a[1]=av0.y; a[2]=av0.z; a[3]=av0.w;
            a[4]=av1.x; a[5]=av1.y; a[6]=av1.z; a[7]=av1.w;
        } else if (g == 1) {
            a[0]=av2.x; a[1]=av2.y; a[2]=av2.z; a[3]=av2.w;
            a[4]=av3.x; a[5]=av3.y; a[6]=av3.z; a[7]=av3.w;
        } else {
            a[0]=av4.x; a[1]=av4.y; a[2]=av4.z; a[3]=av4.w;
            a[4]=av5.x; a[5]=av5.y; a[6]=av5.z; a[7]=av5.w;
        }

        // --- Phase A: u_j = qO_j * q_j for 8 joints (independent, ILP) ---
        float U[G][4];
        float OT[G][3];
        #pragma unroll
        for (int u = 0; u < G; ++u) {
            const int j = g * G + u;
            const float4 qo = *reinterpret_cast<const float4*>(&sQK[j*8]);
            const float4 ot = *reinterpret_cast<const float4*>(&sQK[j*8+4]);
            const float4 ax = *reinterpret_cast<const float4*>(&sAx[j*4]);
            OT[u][0] = ot.x; OT[u][1] = ot.y; OT[u][2] = ot.z;

            const float h = 0.5f * a[u];
            const float s = __sinf(h);
            const float c = __cosf(h);
            const float bx = s * ax.x, by = s * ax.y, bz = s * ax.z;

            U[u][0] = qo.x*c  - qo.y*bx - qo.z*by - qo.w*bz;
            U[u][1] = qo.x*bx + qo.y*c  + qo.z*bz - qo.w*by;
            U[u][2] = qo.x*by - qo.y*bz + qo.z*c  + qo.w*bx;
            U[u][3] = qo.x*bz + qo.y*by - qo.z*bx + qo.w*c;
        }

        // --- Phase B: serial chain, short dep path ---
        #pragma unroll
        for (int u = 0; u < G; ++u) {
            const int j = g * G + u;
            const float ox = OT[u][0], oy = OT[u][1], oz = OT[u][2];

            // t_child = t + R(Q)*O_t   (v' = v + 2*qv x (qv x v + w v))
            const float cx = Qy*oz - Qz*oy + Qw*ox;
            const float cy = Qz*ox - Qx*oz + Qw*oy;
            const float cz = Qx*oy - Qy*ox + Qw*oz;
            const float dx = Qy*cz - Qz*cy;
            const float dy = Qz*cx - Qx*cz;
            const float dz = Qx*cy - Qy*cx;
            tx = tx + ox + 2.f*dx;
            ty = ty + oy + 2.f*dy;
            tz = tz + oz + 2.f*dz;

            // Q = Q * U[u]   (Hamilton)
            const float uw = U[u][0], ux = U[u][1], uy = U[u][2], uz = U[u][3];
            const float nw = Qw*uw - Qx*ux - Qy*uy - Qz*uz;
            const float nx = Qw*ux + Qx*uw + Qy*uz - Qz*uy;
            const float ny = Qw*uy - Qx*uz + Qy*uw + Qz*ux;
            const float nz = Qw*uz + Qx*uy - Qy*ux + Qz*uw;
            Qw = nw; Qx = nx; Qy = ny; Qz = nz;

            srow[3 + 3*j + 0] = tx;
            srow[3 + 3*j + 1] = ty;
            srow[3 + 3*j + 2] = tz;
        }
    }

    __syncthreads();

    // Fully-unrolled coalesced drain: 18 full rounds + 192-thread tail.
    // Nontemporal: write-once data, skip L2 residency.
    vf4* out4 = reinterpret_cast<vf4*>(out + (size_t)blockIdx.x * BLK * 75);
    const vf4* st4 = reinterpret_cast<const vf4*>(stage);
    #pragma unroll
    for (int k = 0; k < 18; ++k) {
        const vf4 v = st4[tid + k * BLK];
        __builtin_nontemporal_store(v, &out4[tid + k * BLK]);
    }
    if (tid < (BLK * 75 / 4) - 18 * BLK) {   // 4800 - 4608 = 192
        const vf4 v = st4[tid + 18 * BLK];
        __builtin_nontemporal_store(v, &out4[tid + 18 * BLK]);
    }
}

extern "C" void kernel_launch(void* const* d_in, const int* in_sizes, int n_in,
                              void* d_out, int out_size, void* d_ws, size_t ws_size,
                              hipStream_t stream) {
    const float* angles = (const float*)d_in[0];
    const float* Torg   = (const float*)d_in[1];
    const float* axes   = (const float*)d_in[2];
    float* out = (float*)d_out;

    const int B = in_sizes[0] / NJ;          // 131072
    const int grid = (B + BLK - 1) / BLK;    // 512

    fk_kernel<<<grid, BLK, 0, stream>>>(angles, Torg, axes, out, B);
}